// Round 1
// baseline (1681.549 us; speedup 1.0000x reference)
//
#include <hip/hip_runtime.h>
#include <math.h>

// Dims
constexpr int NBIN = 31;
constexpr int BB   = 128;
constexpr int TT   = 30;
constexpr int CC   = 256;
constexpr int BT   = BB*TT;     // 3840
constexpr int BTC  = BT*CC;     // 983040
constexpr int NCLS = 10000;

// ---------------------------------------------------------------------------
// K1: strip pooling  x[B,C,T,16,11] -> p[31, B*T, C]  (p[bin][(b*T+t)*C + c])
// 16 patches (consecutive c, same b,t) per 256-thread block.
// ---------------------------------------------------------------------------
__global__ __launch_bounds__(256) void k_pool(const float* __restrict__ x,
                                              float* __restrict__ p) {
  __shared__ float xs[16*180];   // 16 patches x 176, pitch 180
  __shared__ float rs[16*17];    // row sums  (pitch 17: conflict-free)
  __shared__ float rm[16*17];    // row maxes
  const int tid  = threadIdx.x;
  const int pid0 = blockIdx.x * 16;        // pid = (b*T+t)*C + c
  const int bt   = pid0 >> 8;
  const int c0   = pid0 & 255;
  const int b    = bt / 30;
  const int t    = bt - b*30;
  const float* xbase = x + ((long)(b*CC + c0)*TT + t) * 176;
  #pragma unroll
  for (int i = 0; i < 11; ++i) {           // 2816 = 11*256 loads
    int elem = tid + i*256;
    int pp = elem / 176;
    int off = elem - pp*176;
    xs[pp*180 + off] = xbase[(long)pp*5280 + off];
  }
  __syncthreads();
  {
    int pp = tid >> 4, j = tid & 15;       // one H-row per thread
    const float* row = &xs[pp*180 + j*11];
    float s = 0.f, m = -INFINITY;
    #pragma unroll
    for (int w = 0; w < 11; ++w) { float v = row[w]; s += v; m = fmaxf(m, v); }
    rs[pp*17 + j] = s; rm[pp*17 + j] = m;
  }
  __syncthreads();
  for (int o = tid; o < 496; o += 256) {   // 16 patches x 31 bins
    int pp = o & 15, bin = o >> 4;
    int rows, r0;
    if      (bin == 0)  { rows = 16; r0 = 0; }
    else if (bin <= 2)  { rows = 8;  r0 = (bin-1)*8; }
    else if (bin <= 6)  { rows = 4;  r0 = (bin-3)*4; }
    else if (bin <= 14) { rows = 2;  r0 = (bin-7)*2; }
    else                { rows = 1;  r0 = bin-15; }
    float s = 0.f, m = -INFINITY;
    for (int j = 0; j < rows; ++j) {
      s += rs[pp*17 + r0 + j];
      m  = fmaxf(m, rm[pp*17 + r0 + j]);
    }
    p[(long)bin*BTC + pid0 + pp] = s / (rows*11.0f) + m;  // mean + max
  }
}

// ---------------------------------------------------------------------------
// K2: Pmax[n,b,c] = max_t p[n,b,t,c]
// ---------------------------------------------------------------------------
__global__ __launch_bounds__(256) void k_pmax(const float* __restrict__ p,
                                              float* __restrict__ pmax) {
  int gid = blockIdx.x*256 + threadIdx.x;       // n*B*C + b*C + c
  int n = gid / (BB*CC);
  int rem = gid - n*BB*CC;
  const float* base = p + (long)n*BTC + (rem >> 8)*TT*CC + (rem & 255);
  float m = -INFINITY;
  #pragma unroll
  for (int t = 0; t < TT; ++t) m = fmaxf(m, base[t*CC]);
  pmax[gid] = m;
}

// ---------------------------------------------------------------------------
// K3: S[n, m, r] = sum_c p[n,m,c] * Wmask[n,c,r]   (m = b*T+t, r=16)
// one row per thread; Wmask via wave-uniform (scalar) loads.
// ---------------------------------------------------------------------------
__global__ __launch_bounds__(256) void k_sgemm(const float* __restrict__ p,
                                               const float* __restrict__ wmask,
                                               float* __restrict__ S) {
  const int n = blockIdx.x / 15;                     // 3840/256 = 15 blocks per bin
  const int m = (blockIdx.x - n*15)*256 + threadIdx.x;
  const float4* prow = (const float4*)(p + (long)n*BTC + (long)m*CC);
  const float4* wm   = (const float4*)(wmask + n*4096); // [c][r] quads
  float acc[16] = {};
  #pragma unroll 2
  for (int cq = 0; cq < 64; ++cq) {
    float4 pv = prow[cq];
    float pj[4] = {pv.x, pv.y, pv.z, pv.w};
    const float4* wr = wm + cq*16;
    #pragma unroll
    for (int j = 0; j < 4; ++j) {
      float4 w0 = wr[4*j], w1 = wr[4*j+1], w2 = wr[4*j+2], w3 = wr[4*j+3];
      acc[0]  = fmaf(pj[j], w0.x, acc[0]);  acc[1]  = fmaf(pj[j], w0.y, acc[1]);
      acc[2]  = fmaf(pj[j], w0.z, acc[2]);  acc[3]  = fmaf(pj[j], w0.w, acc[3]);
      acc[4]  = fmaf(pj[j], w1.x, acc[4]);  acc[5]  = fmaf(pj[j], w1.y, acc[5]);
      acc[6]  = fmaf(pj[j], w1.z, acc[6]);  acc[7]  = fmaf(pj[j], w1.w, acc[7]);
      acc[8]  = fmaf(pj[j], w2.x, acc[8]);  acc[9]  = fmaf(pj[j], w2.y, acc[9]);
      acc[10] = fmaf(pj[j], w2.z, acc[10]); acc[11] = fmaf(pj[j], w2.w, acc[11]);
      acc[12] = fmaf(pj[j], w3.x, acc[12]); acc[13] = fmaf(pj[j], w3.y, acc[13]);
      acc[14] = fmaf(pj[j], w3.z, acc[14]); acc[15] = fmaf(pj[j], w3.w, acc[15]);
    }
  }
  float4* o = (float4*)(S + ((long)n*BT + m)*16);
  o[0] = make_float4(acc[0],acc[1],acc[2],acc[3]);
  o[1] = make_float4(acc[4],acc[5],acc[6],acc[7]);
  o[2] = make_float4(acc[8],acc[9],acc[10],acc[11]);
  o[3] = make_float4(acc[12],acc[13],acc[14],acc[15]);
}

// ---------------------------------------------------------------------------
// K4: softmax over t, in place. one (n,b,r) per thread.
// ---------------------------------------------------------------------------
__global__ __launch_bounds__(256) void k_softmax(float* __restrict__ S) {
  int gid = blockIdx.x*256 + threadIdx.x;   // 31*128*16 = 63488 exact
  int nb = gid >> 4;
  int r  = gid & 15;
  float* base = S + (long)nb*TT*16 + r;
  float mx = -INFINITY;
  #pragma unroll
  for (int t = 0; t < TT; ++t) mx = fmaxf(mx, base[t*16]);
  float e[TT]; float sum = 0.f;
  #pragma unroll
  for (int t = 0; t < TT; ++t) { e[t] = __expf(base[t*16] - mx); sum += e[t]; }
  float inv = 1.0f / sum;
  #pragma unroll
  for (int t = 0; t < TT; ++t) base[t*16] = e[t]*inv;
}

// ---------------------------------------------------------------------------
// K5: pooled[n,b, c*16+r] = sum_t p[n,b,t,c]*mask[n,b,t,r]. block=(n,b), thread=c.
// mask loads are wave-uniform -> scalar path.
// ---------------------------------------------------------------------------
__global__ __launch_bounds__(256) void k_pooled(const float* __restrict__ p,
                                                const float* __restrict__ mask,
                                                float* __restrict__ pooled) {
  int nb = blockIdx.x;
  int c  = threadIdx.x;
  const float*  pb = p + (long)nb*TT*CC + c;    // n*BTC + b*T*C == nb*7680
  const float4* mk = (const float4*)(mask + (long)nb*TT*16);
  float acc[16] = {};
  for (int t = 0; t < TT; ++t) {
    float pv = pb[t*CC];
    float4 m0 = mk[t*4], m1 = mk[t*4+1], m2 = mk[t*4+2], m3 = mk[t*4+3];
    acc[0]  = fmaf(pv, m0.x, acc[0]);  acc[1]  = fmaf(pv, m0.y, acc[1]);
    acc[2]  = fmaf(pv, m0.z, acc[2]);  acc[3]  = fmaf(pv, m0.w, acc[3]);
    acc[4]  = fmaf(pv, m1.x, acc[4]);  acc[5]  = fmaf(pv, m1.y, acc[5]);
    acc[6]  = fmaf(pv, m1.z, acc[6]);  acc[7]  = fmaf(pv, m1.w, acc[7]);
    acc[8]  = fmaf(pv, m2.x, acc[8]);  acc[9]  = fmaf(pv, m2.y, acc[9]);
    acc[10] = fmaf(pv, m2.z, acc[10]); acc[11] = fmaf(pv, m2.w, acc[11]);
    acc[12] = fmaf(pv, m3.x, acc[12]); acc[13] = fmaf(pv, m3.y, acc[13]);
    acc[14] = fmaf(pv, m3.z, acc[14]); acc[15] = fmaf(pv, m3.w, acc[15]);
  }
  float4* o = (float4*)(pooled + (long)nb*4096 + c*16);
  o[0] = make_float4(acc[0],acc[1],acc[2],acc[3]);
  o[1] = make_float4(acc[4],acc[5],acc[6],acc[7]);
  o[2] = make_float4(acc[8],acc[9],acc[10],acc[11]);
  o[3] = make_float4(acc[12],acc[13],acc[14],acc[15]);
}

// ---------------------------------------------------------------------------
// K6: out = pooled[n](128x4096) @ Wout[n](4096x256). 128x128 tile, 8x8/thread,
// K split 8-way -> partial sums into outacc8[ks][n,b,c] (no atomics).
// grid = 31 * 2(ntile) * 8(ksplit) = 496
// ---------------------------------------------------------------------------
__global__ __launch_bounds__(256,2) void k_outgemm(const float* __restrict__ A_,
                                                   const float* __restrict__ Bw,
                                                   float* __restrict__ outacc8) {
  __shared__ float As[32*132];
  __shared__ float Bs[32*132];
  const int bx = blockIdx.x;
  const int n  = bx >> 4;
  const int rem = bx & 15;
  const int n0  = (rem >> 3) * 128;
  const int ks  = rem & 7;
  const int kbase = ks * 512;
  const int tid = threadIdx.x;
  const float4* A4 = (const float4*)(A_ + (long)n*524288);   // [128][4096]
  const float4* B4 = (const float4*)(Bw + (long)n*1048576);  // [4096][256]
  float acc[8][8] = {};
  const int rg = tid >> 4, cg = tid & 15;
  for (int kt = 0; kt < 16; ++kt) {
    int k0 = kbase + kt*32;
    #pragma unroll
    for (int i = 0; i < 4; ++i) {          // A tile 128x32, store transposed
      int qq = tid + i*256;
      int mm = qq >> 3, kq = qq & 7;
      float4 v = A4[mm*1024 + (k0>>2) + kq];
      As[(kq*4+0)*132 + mm] = v.x;
      As[(kq*4+1)*132 + mm] = v.y;
      As[(kq*4+2)*132 + mm] = v.z;
      As[(kq*4+3)*132 + mm] = v.w;
    }
    #pragma unroll
    for (int i = 0; i < 4; ++i) {          // B tile 32x128
      int qq = tid + i*256;
      int kk = qq >> 5, cq = qq & 31;
      *(float4*)&Bs[kk*132 + cq*4] = B4[(k0+kk)*64 + (n0>>2) + cq];
    }
    __syncthreads();
    #pragma unroll
    for (int kk = 0; kk < 32; ++kk) {
      float4 a0 = *(const float4*)&As[kk*132 + rg*8];
      float4 a1 = *(const float4*)&As[kk*132 + rg*8 + 4];
      float4 b0 = *(const float4*)&Bs[kk*132 + cg*8];
      float4 b1 = *(const float4*)&Bs[kk*132 + cg*8 + 4];
      float av[8] = {a0.x,a0.y,a0.z,a0.w,a1.x,a1.y,a1.z,a1.w};
      float bv[8] = {b0.x,b0.y,b0.z,b0.w,b1.x,b1.y,b1.z,b1.w};
      #pragma unroll
      for (int i = 0; i < 8; ++i)
        #pragma unroll
        for (int j = 0; j < 8; ++j)
          acc[i][j] = fmaf(av[i], bv[j], acc[i][j]);
    }
    __syncthreads();
  }
  float* dst = outacc8 + (long)ks*1015808 + (long)(n*BB)*CC;
  #pragma unroll
  for (int i = 0; i < 8; ++i) {
    int m = rg*8 + i;
    float4* o = (float4*)&dst[m*CC + n0 + cg*8];
    o[0] = make_float4(acc[i][0],acc[i][1],acc[i][2],acc[i][3]);
    o[1] = make_float4(acc[i][4],acc[i][5],acc[i][6],acc[i][7]);
  }
}

// ---------------------------------------------------------------------------
// K7: feat = Pmax + leaky(sum_ks outacc8)   (residual+max over T collapses)
// ---------------------------------------------------------------------------
__global__ __launch_bounds__(256) void k_feat(const float* __restrict__ oacc,
                                              const float* __restrict__ pmax,
                                              float* __restrict__ feat) {
  int idx = blockIdx.x*256 + threadIdx.x;
  float v = 0.f;
  #pragma unroll
  for (int s = 0; s < 8; ++s) v += oacc[(long)s*1015808 + idx];
  v = (v >= 0.f) ? v : 0.01f*v;
  feat[idx] = pmax[idx] + v;
}

// ---------------------------------------------------------------------------
// K8: outputs = feat[n](128x256) @ FForward[n](256x256); write ws copy + out0
// (transposed to [B,31,256]). feat reads are wave-uniform -> scalar path.
// ---------------------------------------------------------------------------
__global__ __launch_bounds__(256) void k_ff(const float* __restrict__ feat,
                                            const float* __restrict__ FF,
                                            float* __restrict__ outw,
                                            float* __restrict__ out0) {
  const int n  = blockIdx.x >> 4;
  const int b0 = (blockIdx.x & 15) << 3;
  const int tid = threadIdx.x;
  const float* F  = FF + n*65536;
  const float* fb = feat + (n*BB + b0)*CC;
  float acc[8] = {};
  #pragma unroll 4
  for (int c = 0; c < CC; ++c) {
    float f = F[c*CC + tid];
    #pragma unroll
    for (int i = 0; i < 8; ++i) acc[i] = fmaf(fb[i*CC + c], f, acc[i]);
  }
  #pragma unroll
  for (int i = 0; i < 8; ++i) {
    int b = b0 + i;
    outw[(n*BB + b)*CC + tid] = acc[i];
    out0[((long)b*NBIN + n)*CC + tid] = acc[i];
  }
}

// K9: per-(n,o) batch stats -> scale/shift
__global__ __launch_bounds__(256) void k_bnstat(const float* __restrict__ outw,
                                                const float* __restrict__ g,
                                                const float* __restrict__ bt,
                                                float* __restrict__ scale,
                                                float* __restrict__ shift) {
  int n = blockIdx.x, o = threadIdx.x;
  const float* base = outw + n*BB*CC + o;
  float s = 0.f, s2 = 0.f;
  #pragma unroll 4
  for (int b = 0; b < BB; ++b) { float v = base[b*CC]; s += v; s2 += v*v; }
  float mean = s * (1.0f/BB);
  float var  = fmaxf(s2 * (1.0f/BB) - mean*mean, 0.f);
  float sc = g[n*CC+o] / sqrtf(var + 1e-5f);
  scale[n*CC+o] = sc;
  shift[n*CC+o] = bt[n*CC+o] - mean*sc;
}

// K10: bn + L2 normalize over o. block=(n,b).
__global__ __launch_bounds__(256) void k_bnn(const float* __restrict__ outw,
                                             const float* __restrict__ scale,
                                             const float* __restrict__ shift,
                                             float* __restrict__ bnn) {
  int nb = blockIdx.x, o = threadIdx.x;
  int n = nb >> 7;
  float v = fmaf(scale[n*CC+o], outw[(long)nb*CC+o], shift[n*CC+o]);
  float s = v*v;
  #pragma unroll
  for (int off = 32; off > 0; off >>= 1) s += __shfl_down(s, off, 64);
  __shared__ float ps[4];
  if ((o & 63) == 0) ps[o >> 6] = s;
  __syncthreads();
  float tot = ps[0] + ps[1] + ps[2] + ps[3];
  float inv = 1.0f / fmaxf(sqrtf(tot), 1e-12f);
  bnn[(long)nb*CC + o] = v * inv;
}

// K11: invn[n,k] = 1/max(||fc1d[n,:,k]||, eps)
__global__ __launch_bounds__(256) void k_invn(const float* __restrict__ fc,
                                              float* __restrict__ invn) {
  int gid = blockIdx.x*256 + threadIdx.x;
  if (gid >= NBIN*NCLS) return;
  int n = gid / NCLS;
  int k = gid - n*NCLS;
  const float* base = fc + (long)n*CC*NCLS + k;
  float s = 0.f;
  #pragma unroll 4
  for (int o = 0; o < CC; ++o) { float v = base[(long)o*NCLS]; s += v*v; }
  invn[gid] = 1.0f / fmaxf(sqrtf(s), 1e-12f);
}

// ---------------------------------------------------------------------------
// K12: logits = bnn[n](128x256) @ fc1d[n](256x10000) * invn, written to
// out1[b,n,k]. 128x128 tile, 8x8/thread. grid = 31*79 = 2449.
// ---------------------------------------------------------------------------
__global__ __launch_bounds__(256,2) void k_logits(const float* __restrict__ Abnn,
                                                  const float* __restrict__ fc,
                                                  const float* __restrict__ invn,
                                                  float* __restrict__ out1) {
  __shared__ float As[32*132];
  __shared__ float Bs[32*132];
  const int bx = blockIdx.x;
  const int n  = bx / 79;
  const int nt = bx - n*79;
  const int n0 = nt * 128;
  const int tid = threadIdx.x;
  const float4* A4 = (const float4*)(Abnn + (long)n*BB*CC);
  const float*  Bm = fc + (long)n*CC*NCLS;
  float acc[8][8] = {};
  const int rg = tid >> 4, cg = tid & 15;
  for (int k0 = 0; k0 < 256; k0 += 32) {
    #pragma unroll
    for (int i = 0; i < 4; ++i) {          // A tile 128x32, transposed
      int qq = tid + i*256;
      int mm = qq >> 3, kq = qq & 7;
      float4 v = A4[mm*64 + (k0>>2) + kq];
      As[(kq*4+0)*132 + mm] = v.x;
      As[(kq*4+1)*132 + mm] = v.y;
      As[(kq*4+2)*132 + mm] = v.z;
      As[(kq*4+3)*132 + mm] = v.w;
    }
    #pragma unroll
    for (int i = 0; i < 4; ++i) {          // B tile 32x128 (bounds-checked)
      int qq = tid + i*256;
      int kk = qq >> 5, cq = qq & 31;
      int col = n0 + cq*4;
      float4 v = make_float4(0.f, 0.f, 0.f, 0.f);
      if (col < NCLS) v = *(const float4*)&Bm[(long)(k0+kk)*NCLS + col];
      *(float4*)&Bs[kk*132 + cq*4] = v;
    }
    __syncthreads();
    #pragma unroll
    for (int kk = 0; kk < 32; ++kk) {
      float4 a0 = *(const float4*)&As[kk*132 + rg*8];
      float4 a1 = *(const float4*)&As[kk*132 + rg*8 + 4];
      float4 b0 = *(const float4*)&Bs[kk*132 + cg*8];
      float4 b1 = *(const float4*)&Bs[kk*132 + cg*8 + 4];
      float av[8] = {a0.x,a0.y,a0.z,a0.w,a1.x,a1.y,a1.z,a1.w};
      float bv[8] = {b0.x,b0.y,b0.z,b0.w,b1.x,b1.y,b1.z,b1.w};
      #pragma unroll
      for (int i = 0; i < 8; ++i)
        #pragma unroll
        for (int j = 0; j < 8; ++j)
          acc[i][j] = fmaf(av[i], bv[j], acc[i][j]);
    }
    __syncthreads();
  }
  const int colb = n0 + cg*8;
  if (colb < NCLS) {        // 10000 % 8 == 0 -> all-or-nothing per thread
    float4 iv0 = *(const float4*)&invn[n*NCLS + colb];
    float4 iv1 = *(const float4*)&invn[n*NCLS + colb + 4];
    float ivv[8] = {iv0.x,iv0.y,iv0.z,iv0.w,iv1.x,iv1.y,iv1.z,iv1.w};
    #pragma unroll
    for (int i = 0; i < 8; ++i) {
      int b = rg*8 + i;
      float4* dst = (float4*)&out1[(long)b*(NBIN*NCLS) + n*NCLS + colb];
      dst[0] = make_float4(acc[i][0]*ivv[0], acc[i][1]*ivv[1],
                           acc[i][2]*ivv[2], acc[i][3]*ivv[3]);
      dst[1] = make_float4(acc[i][4]*ivv[4], acc[i][5]*ivv[5],
                           acc[i][6]*ivv[6], acc[i][7]*ivv[7]);
    }
  }
}

extern "C" void kernel_launch(void* const* d_in, const int* in_sizes, int n_in,
                              void* d_out, int out_size, void* d_ws, size_t ws_size,
                              hipStream_t stream) {
  const float* x     = (const float*)d_in[0];
  const float* wmask = (const float*)d_in[1];
  const float* wout  = (const float*)d_in[2];
  const float* ff    = (const float*)d_in[3];
  const float* gamma = (const float*)d_in[4];
  const float* beta  = (const float*)d_in[5];
  const float* fc1d  = (const float*)d_in[6];
  float* out0 = (float*)d_out;               // [B,31,256]
  float* out1 = out0 + 1015808;              // [B,31,10000]

  float* ws = (float*)d_ws;                  // high-water: ~212 MB
  float* p      = ws;                        // 30,474,240  [31][3840][256]
  float* pooled = ws + 30474240;             // 16,252,928  [31][128][4096]
  float* pmax   = ws + 46727168;             //  1,015,808
  float* feat   = ws + 47742976;             //  1,015,808
  float* outw   = ws + 48758784;             //  1,015,808
  float* scale  = ws + 49774592;             //      7,936
  float* shift  = ws + 49782528;             //      7,936
  float* bnnb   = ws + 49790464;             //  1,015,808
  float* invn   = ws + 50806272;             //    310,000
  float* smask  = ws + 51116272;             //  1,904,640  [31][128][30][16]
  float* outacc8 = ws;                       // 8,126,464 — aliases p (dead by then)

  k_pool   <<<61440, 256, 0, stream>>>(x, p);
  k_pmax   <<<3968,  256, 0, stream>>>(p, pmax);
  k_sgemm  <<<465,   256, 0, stream>>>(p, wmask, smask);
  k_softmax<<<248,   256, 0, stream>>>(smask);
  k_pooled <<<3968,  256, 0, stream>>>(p, smask, pooled);
  k_outgemm<<<496,   256, 0, stream>>>(pooled, wout, outacc8);
  k_feat   <<<3968,  256, 0, stream>>>(outacc8, pmax, feat);
  k_ff     <<<496,   256, 0, stream>>>(feat, ff, outw, out0);
  k_bnstat <<<31,    256, 0, stream>>>(outw, gamma, beta, scale, shift);
  k_bnn    <<<3968,  256, 0, stream>>>(outw, scale, shift, bnnb);
  k_invn   <<<1211,  256, 0, stream>>>(fc1d, invn);
  k_logits <<<2449,  256, 0, stream>>>(bnnb, fc1d, invn, out1);
}